// Round 1
// baseline (245.944 us; speedup 1.0000x reference)
//
#include <hip/hip_runtime.h>
#include <math.h>

// Problem dims (compile-time constants)
#define B_   512
#define F_   1024
#define H1_  512
#define H2_  256
#define OUT_ 128
#define KD_  5
#define NT_  (OUT_ * KD_)   // 640

__device__ __forceinline__ float lrelu(float v) {
    return v >= 0.f ? v : 0.2f * v;
}

// ---------------------------------------------------------------------------
// Tiled fp32 GEMM: C[M,N] = act(A[M,K] @ B[K,N] + bias[N])
// All of M, N, K are multiples of TILE (verified for every call site).
// ---------------------------------------------------------------------------
template<int TILE, bool RELU, bool HAS_BIAS>
__global__ void gemm_bias(const float* __restrict__ A, const float* __restrict__ Bm,
                          const float* __restrict__ bias, float* __restrict__ C,
                          int M, int N, int K) {
    __shared__ float As[TILE][TILE + 1];
    __shared__ float Bs[TILE][TILE + 1];
    const int tx = threadIdx.x, ty = threadIdx.y;
    const int row = blockIdx.y * TILE + ty;
    const int col = blockIdx.x * TILE + tx;
    float acc = 0.f;
    for (int k0 = 0; k0 < K; k0 += TILE) {
        As[ty][tx] = A[row * K + k0 + tx];        // coalesced in tx
        Bs[ty][tx] = Bm[(k0 + ty) * N + col];     // coalesced in tx
        __syncthreads();
        #pragma unroll
        for (int kk = 0; kk < TILE; ++kk)
            acc += As[ty][kk] * Bs[kk][tx];
        __syncthreads();
    }
    if (HAS_BIAS) acc += bias[col];
    if (RELU) acc = lrelu(acc);
    C[row * N + col] = acc;
}

// ---------------------------------------------------------------------------
// Minibatch discrimination:
//   M: (B, OUT, KD) row-major -> M[i*640 + o*5 + k]
//   o_b[j, o] = sum_i exp(-sum_k |M[i,o,k] - M[j,o,k]|) - 1
// One block per j (128 threads = one o each), loop over i. M (1.25 MB) is
// L2-resident so the stride-5 gather is served from cache.
// ---------------------------------------------------------------------------
__global__ void minibatch_disc(const float* __restrict__ Mm, float* __restrict__ o_b) {
    const int j = blockIdx.x;
    const int o = threadIdx.x;            // 0..127
    float mj[KD_];
    #pragma unroll
    for (int k = 0; k < KD_; ++k) mj[k] = Mm[j * NT_ + o * KD_ + k];
    float acc = 0.f;
    for (int i = 0; i < B_; ++i) {
        const float* mi = &Mm[i * NT_ + o * KD_];
        float norm = 0.f;
        #pragma unroll
        for (int k = 0; k < KD_; ++k) norm += fabsf(mi[k] - mj[k]);
        acc += __expf(-norm);
    }
    o_b[j * OUT_ + o] = acc - 1.f;        // -1 removes the i==j self term
}

// ---------------------------------------------------------------------------
// z = concat([h2 (B x 256), o_b (B x 128)], axis=1) -> (B x 384)
// ---------------------------------------------------------------------------
__global__ void concat_kernel(const float* __restrict__ h2, const float* __restrict__ ob,
                              float* __restrict__ z) {
    const int idx = blockIdx.x * blockDim.x + threadIdx.x;   // B*384 threads
    const int m = idx / (H2_ + OUT_);
    const int c = idx % (H2_ + OUT_);
    z[idx] = (c < H2_) ? h2[m * H2_ + c] : ob[m * OUT_ + (c - H2_)];
}

// ---------------------------------------------------------------------------
// out[m] = dot(z3[m,:], W4[:,0]) + b4   (K = 128)
// ---------------------------------------------------------------------------
__global__ void final_dot(const float* __restrict__ z3, const float* __restrict__ W4,
                          const float* __restrict__ b4, float* __restrict__ out) {
    const int m = blockIdx.x * blockDim.x + threadIdx.x;     // 512 threads
    float acc = 0.f;
    #pragma unroll 4
    for (int k = 0; k < OUT_; ++k) acc += z3[m * OUT_ + k] * W4[k];
    out[m] = acc + b4[0];
}

extern "C" void kernel_launch(void* const* d_in, const int* in_sizes, int n_in,
                              void* d_out, int out_size, void* d_ws, size_t ws_size,
                              hipStream_t stream) {
    const float* x  = (const float*)d_in[0];   // (512, 1024)
    const float* W1 = (const float*)d_in[1];   // (1024, 512)
    const float* b1 = (const float*)d_in[2];   // (512,)
    const float* W2 = (const float*)d_in[3];   // (512, 256)
    const float* b2 = (const float*)d_in[4];   // (256,)
    const float* T  = (const float*)d_in[5];   // (256, 128, 5) -> view (256, 640)
    const float* W3 = (const float*)d_in[6];   // (384, 128)
    const float* b3 = (const float*)d_in[7];   // (384,)? no: (128,)
    const float* W4 = (const float*)d_in[8];   // (128, 1)
    const float* b4 = (const float*)d_in[9];   // (1,)
    float* out = (float*)d_out;                // (512, 1) = 512 floats

    // Workspace layout (floats)
    float* ws  = (float*)d_ws;
    float* h1  = ws;                                   // 512*512
    float* h2  = h1 + B_ * H1_;                        // 512*256
    float* Mm  = h2 + B_ * H2_;                        // 512*640
    float* ob  = Mm + B_ * NT_;                        // 512*128
    float* z   = ob + B_ * OUT_;                       // 512*384
    float* z3  = z  + B_ * (H2_ + OUT_);               // 512*128
    // total = 1,048,576 floats = 4 MB

    const dim3 blk(32, 32);

    // h1 = lrelu(x @ W1 + b1)            (512 x 512), K=1024
    gemm_bias<32, true, true><<<dim3(H1_ / 32, B_ / 32), blk, 0, stream>>>(
        x, W1, b1, h1, B_, H1_, F_);

    // h2 = lrelu(h1 @ W2 + b2)           (512 x 256), K=512
    gemm_bias<32, true, true><<<dim3(H2_ / 32, B_ / 32), blk, 0, stream>>>(
        h1, W2, b2, h2, B_, H2_, H1_);

    // M = h2 @ T.reshape(256, 640)       (512 x 640), K=256
    gemm_bias<32, false, false><<<dim3(NT_ / 32, B_ / 32), blk, 0, stream>>>(
        h2, T, nullptr, Mm, B_, NT_, H2_);

    // o_b = minibatch discrimination     (512 x 128)
    minibatch_disc<<<B_, OUT_, 0, stream>>>(Mm, ob);

    // z = concat([h2, o_b], 1)           (512 x 384)
    concat_kernel<<<(B_ * (H2_ + OUT_)) / 256, 256, 0, stream>>>(h2, ob, z);

    // z3 = lrelu(z @ W3 + b3)            (512 x 128), K=384
    gemm_bias<32, true, true><<<dim3(OUT_ / 32, B_ / 32), blk, 0, stream>>>(
        z, W3, b3, z3, B_, OUT_, H2_ + OUT_);

    // out = z3 @ W4 + b4                 (512 x 1), K=128
    final_dot<<<B_ / 256, 256, 0, stream>>>(z3, W4, b4, out);
}

// Round 2
// 166.420 us; speedup vs baseline: 1.4778x; 1.4778x over previous
//
#include <hip/hip_runtime.h>
#include <math.h>

// Problem dims (compile-time constants)
#define B_   512
#define F_   1024
#define H1_  512
#define H2_  256
#define OUT_ 128
#define KD_  5
#define NT_  (OUT_ * KD_)   // 640

__device__ __forceinline__ float lrelu(float v) {
    return v >= 0.f ? v : 0.2f * v;
}

// ---------------------------------------------------------------------------
// Register-tiled fp32 GEMM: C = act(A @ B + bias)
// 32x32 block tile, 256 threads, 2x2 micro-tile per thread, K-tile = 32,
// register prefetch of the next K-tile (hides global latency across barrier).
// M, N, K must be multiples of 32 (true at every call site).
// CONCAT_A: A-operand is concat([A (ld 256), A2 (ld 128)], axis=1), K=384.
// TRANS_OUT: store C transposed, C[col*M + row] (used to produce Mt).
// ---------------------------------------------------------------------------
template<bool RELU, bool HAS_BIAS, bool TRANS_OUT, bool CONCAT_A>
__global__ __launch_bounds__(256, 2)
void gemm32(const float* __restrict__ A, const float* __restrict__ A2,
            const float* __restrict__ Bm, const float* __restrict__ bias,
            float* __restrict__ C, int M, int N, int K)
{
    __shared__ float As[32][33];   // [kk][row]  (+1 pad: staging stores are stride-33)
    __shared__ float Bs[32][33];   // [kk][col]
    const int tid  = threadIdx.x;
    const int tx   = tid & 15;     // micro-tile col group (2 cols)
    const int ty   = tid >> 4;     // micro-tile row group (2 rows)
    const int m0   = blockIdx.y * 32;
    const int n0   = blockIdx.x * 32;
    const int lrow = tid >> 5;     // 0..7   staging row base
    const int lcol = tid & 31;     // 0..31  staging inner index (coalesced)

    float pa[4], pb[4];
    #pragma unroll
    for (int q = 0; q < 4; ++q) {
        const int arow = m0 + lrow + 8 * q;
        const int akk  = lcol;
        if (CONCAT_A)
            pa[q] = (akk < H2_) ? A[arow * H2_ + akk] : A2[arow * OUT_ + (akk - H2_)];
        else
            pa[q] = A[arow * K + akk];
        pb[q] = Bm[(lrow + 8 * q) * N + n0 + lcol];
    }

    float acc00 = 0.f, acc01 = 0.f, acc10 = 0.f, acc11 = 0.f;

    for (int k0 = 0; k0 < K; k0 += 32) {
        #pragma unroll
        for (int q = 0; q < 4; ++q) {
            As[lcol][lrow + 8 * q] = pa[q];   // transpose into [kk][row]
            Bs[lrow + 8 * q][lcol] = pb[q];
        }
        __syncthreads();

        if (k0 + 32 < K) {                    // prefetch next K-tile
            #pragma unroll
            for (int q = 0; q < 4; ++q) {
                const int arow = m0 + lrow + 8 * q;
                const int akk  = k0 + 32 + lcol;
                if (CONCAT_A)
                    pa[q] = (akk < H2_) ? A[arow * H2_ + akk] : A2[arow * OUT_ + (akk - H2_)];
                else
                    pa[q] = A[arow * K + akk];
                pb[q] = Bm[(k0 + 32 + lrow + 8 * q) * N + n0 + lcol];
            }
        }

        #pragma unroll
        for (int kk = 0; kk < 32; ++kk) {
            const float a0 = As[kk][2 * ty];
            const float a1 = As[kk][2 * ty + 1];
            const float b0 = Bs[kk][2 * tx];
            const float b1 = Bs[kk][2 * tx + 1];
            acc00 += a0 * b0; acc01 += a0 * b1;
            acc10 += a1 * b0; acc11 += a1 * b1;
        }
        __syncthreads();
    }

    const int row = m0 + 2 * ty;
    const int col = n0 + 2 * tx;
    float v[2][2] = {{acc00, acc01}, {acc10, acc11}};
    #pragma unroll
    for (int r = 0; r < 2; ++r)
        #pragma unroll
        for (int c = 0; c < 2; ++c) {
            float u = v[r][c];
            if (HAS_BIAS) u += bias[col + c];
            if (RELU) u = lrelu(u);
            if (TRANS_OUT) C[(col + c) * M + (row + r)] = u;
            else           C[(row + r) * N + (col + c)] = u;
        }
}

// ---------------------------------------------------------------------------
// Minibatch discrimination from transposed M:
//   Mt: [NT_=640][B_=512], row n = o*5+k holds M[:, o, k] contiguously.
//   o_b[j, o] = sum_i exp(-sum_k |Mt[o*5+k][i] - Mt[o*5+k][j]|) - 1
// Block = (o, j-half): 256 blocks x 256 threads. Stage this o's 5x512 floats
// (10 KB) into LDS once (float4 coalesced); inner loop reads are wave-wide
// broadcasts (conflict-free); mj lives in registers.
// ---------------------------------------------------------------------------
__global__ __launch_bounds__(256)
void minibatch_disc(const float* __restrict__ Mt, float* __restrict__ o_b) {
    __shared__ float L[KD_ * B_];          // [k][i] flat = k*512 + i
    const int o = blockIdx.x >> 1;
    const int j = (blockIdx.x & 1) * 256 + threadIdx.x;
    const float4* src = (const float4*)(Mt + o * KD_ * B_);
    float4* dst = (float4*)L;
    for (int e = threadIdx.x; e < (KD_ * B_) / 4; e += 256)
        dst[e] = src[e];
    __syncthreads();

    const float mj0 = L[0 * B_ + j], mj1 = L[1 * B_ + j], mj2 = L[2 * B_ + j],
                mj3 = L[3 * B_ + j], mj4 = L[4 * B_ + j];
    float accA = 0.f, accB = 0.f;
    #pragma unroll 4
    for (int i = 0; i < B_; i += 2) {
        {
            float n0 = fabsf(L[0 * B_ + i] - mj0) + fabsf(L[1 * B_ + i] - mj1);
            float n1 = fabsf(L[2 * B_ + i] - mj2) + fabsf(L[3 * B_ + i] - mj3);
            accA += __expf(-(n0 + n1 + fabsf(L[4 * B_ + i] - mj4)));
        }
        {
            const int i2 = i + 1;
            float n0 = fabsf(L[0 * B_ + i2] - mj0) + fabsf(L[1 * B_ + i2] - mj1);
            float n1 = fabsf(L[2 * B_ + i2] - mj2) + fabsf(L[3 * B_ + i2] - mj3);
            accB += __expf(-(n0 + n1 + fabsf(L[4 * B_ + i2] - mj4)));
        }
    }
    o_b[j * OUT_ + o] = accA + accB - 1.f;   // -1 removes the i==j self term
}

// ---------------------------------------------------------------------------
// out[m] = dot(z3[m,:], W4[:,0]) + b4   (K = 128), float4 reads
// ---------------------------------------------------------------------------
__global__ void final_dot(const float* __restrict__ z3, const float* __restrict__ W4,
                          const float* __restrict__ b4, float* __restrict__ out) {
    const int m = blockIdx.x * 256 + threadIdx.x;
    const float4* zr = (const float4*)(z3 + m * OUT_);
    const float4* w  = (const float4*)W4;
    float acc = 0.f;
    #pragma unroll
    for (int k = 0; k < OUT_ / 4; ++k) {
        float4 a = zr[k], b = w[k];
        acc += a.x * b.x + a.y * b.y + a.z * b.z + a.w * b.w;
    }
    out[m] = acc + b4[0];
}

extern "C" void kernel_launch(void* const* d_in, const int* in_sizes, int n_in,
                              void* d_out, int out_size, void* d_ws, size_t ws_size,
                              hipStream_t stream) {
    const float* x  = (const float*)d_in[0];   // (512, 1024)
    const float* W1 = (const float*)d_in[1];   // (1024, 512)
    const float* b1 = (const float*)d_in[2];   // (512,)
    const float* W2 = (const float*)d_in[3];   // (512, 256)
    const float* b2 = (const float*)d_in[4];   // (256,)
    const float* T  = (const float*)d_in[5];   // (256, 640) flat view
    const float* W3 = (const float*)d_in[6];   // (384, 128)
    const float* b3 = (const float*)d_in[7];   // (128,)
    const float* W4 = (const float*)d_in[8];   // (128, 1)
    const float* b4 = (const float*)d_in[9];   // (1,)
    float* out = (float*)d_out;                // (512, 1)

    float* ws = (float*)d_ws;
    float* h1 = ws;                        // 512*512
    float* h2 = h1 + B_ * H1_;             // 512*256
    float* Mt = h2 + B_ * H2_;             // 640*512 (transposed M)
    float* ob = Mt + NT_ * B_;             // 512*128
    float* z3 = ob + B_ * OUT_;            // 512*128
    // total = 851,968 floats = 3.25 MB

    // h1 = lrelu(x @ W1 + b1)            (512 x 512), K=1024
    gemm32<true, true, false, false><<<dim3(H1_ / 32, B_ / 32), 256, 0, stream>>>(
        x, nullptr, W1, b1, h1, B_, H1_, F_);

    // h2 = lrelu(h1 @ W2 + b2)           (512 x 256), K=512
    gemm32<true, true, false, false><<<dim3(H2_ / 32, B_ / 32), 256, 0, stream>>>(
        h1, nullptr, W2, b2, h2, B_, H2_, H1_);

    // Mt = (h2 @ T)^T                    (640 x 512), K=256, stored transposed
    gemm32<false, false, true, false><<<dim3(NT_ / 32, B_ / 32), 256, 0, stream>>>(
        h2, nullptr, T, nullptr, Mt, B_, NT_, H2_);

    // o_b (512 x 128)
    minibatch_disc<<<256, 256, 0, stream>>>(Mt, ob);

    // z3 = lrelu(concat([h2, ob]) @ W3 + b3)   (512 x 128), K=384
    gemm32<true, true, false, true><<<dim3(OUT_ / 32, B_ / 32), 256, 0, stream>>>(
        h2, ob, W3, b3, z3, B_, OUT_, H2_ + OUT_);

    // out = z3 @ W4 + b4                 (512 x 1)
    final_dot<<<B_ / 256, 256, 0, stream>>>(z3, W4, b4, out);
}